// Round 9
// baseline (2208.466 us; speedup 1.0000x reference)
//
#include <hip/hip_runtime.h>

// ModalVerlet: B=16, M=64, T=48000. 3-wave specialization: 1 scan + 2 storers.
//
// Wave 0 (scan) — identical math to R7/R8 (absmax 2.0): step s =
//   rNew=rcp(aPrev); hs=fma(phe,fe,g2); cz=fma(mom2C,z,hs); kl=fma(m2g2,rU,cz);
//   W=fma(CAu,u,z); zn=fma(CAGB,kl,W); un=fma(Fd,u,kl); e=exp2(zn); a=ePrev+1.
//   7 VALU + 2 trans, 3-fma loop chain, trans latency pipelined.
//
// R9 change (the one experiment): fe refills moved AFTER __syncthreads.
// __syncthreads lowers to s_waitcnt vmcnt(0) lgkmcnt(0); s_barrier — R5-R8
// issued the 8 fe global_load_dwordx4 immediately BEFORE the barrier, exposing
// full HBM latency (~900cyc/tile ~ 28 cyc/step) at every drain. That constant
// term explains the flat ~70-85 cyc/step across R4-R8 regardless of scan math.
// Refill-after-barrier gives loads a full tile (~1000cyc) to complete before
// the next drain; consumed 2 tiles later (bufA: refilled end of tile j, read
// in tile j+2) -> correctness unchanged.
//
// Waves 1,2 (storers): as R8 — alternate tiles, tile split across two barrier
// intervals (phase A: dq/dp[0..3] at interval j, phase B: [4..7] at j+1);
// 4-slot LDS ring keeps data live. p_s = Gd*(u_s+u_{s+1}) (exact); boundary u
// from next tile's entry 0; final u via pseudo-entry + one extra barrier.

#define NB 16
#define NM 64
#define NT 48000
#define SPI 32
#define NITER (NT / SPI) // 1500
#define NSLOT 4

__global__ void __launch_bounds__(192, 1) modal_scan_kernel(
    const float* __restrict__ y0,
    const float* __restrict__ omega,
    const float* __restrict__ sigma,
    const float* __restrict__ gamma,
    const float* __restrict__ Phi_e,
    const float* __restrict__ fe_points,
    float* __restrict__ y_out)
{
    const int b   = blockIdx.x;
    const int wid = threadIdx.x >> 6;
    const int m   = threadIdx.x & 63;

    __shared__ float4 lzu[NSLOT][SPI / 2][NM]; // (z_t,u_t,z_{t+1},u_{t+1}) ; 64 KB

    const float k    = 1.0f / 48000.0f;
    const float k2   = 0.5f * k;
    const float invC = 0.34657359027997264f; // ln(2)/2

    if (wid == 0) {
        // ---------------- scan wave ----------------
        const float om  = omega[b * NM + m];
        const float sg  = sigma[b * NM + m];
        const float g   = gamma[b];
        const float phe = Phi_e[b * NM + m];
        const float om2 = om * om;
        const float g2  = g * g;

        const float E    = 1.0f - k * sg;
        const float dinv = 1.0f / (1.0f + k * sg);
        const float A    = k * E;
        const float Bc   = k * k2;
        const float Fd   = E * dinv;
        const float Gd   = k2 * dinv;
        const float AGB  = A * Gd + Bc;
        const float m2g2 = -2.0f * g2;

        const float C    = 2.885390081777927f;   // 2*log2(e)
        const float CA   = C * A;
        const float CAGB = C * AGB;
        const float mom2C = -om2 * invC;
        const float GdF1 = Gd * (1.0f + Fd);
        const float CAu  = CA * GdF1;

        const float q0v = y0[b * 2 * NM + m];
        const float p0v = y0[b * 2 * NM + NM + m];

        const float4* fe4 = reinterpret_cast<const float4*>(fe_points + (size_t)b * NT);

        float4 bufA[8], bufB[8];
#pragma unroll
        for (int i = 0; i < 8; ++i) bufA[i] = fe4[i];
#pragma unroll
        for (int i = 0; i < 8; ++i) bufB[i] = fe4[8 + i];

        // ---- preamble: state 0 + trans pipeline priming ----
        float z  = C * q0v;
        float e0 = __builtin_amdgcn_exp2f(z);
        float a0 = e0 + 1.0f;
        float r0 = __builtin_amdgcn_rcpf(a0);
        float u;
        {
            float hs0 = fmaf(phe, bufA[0].x, g2);
            float cz0 = fmaf(mom2C, z, hs0);
            float c0  = fmaf(m2g2, r0, cz0);
            u = fmaf(-Gd, c0, p0v) / GdF1;   // u_0 : p_0 = Gd*(u_0+u_1)
        }
        float rU = r0, aPrev = a0, ePrev = e0;

#define STEP(FE) {                                        \
    float rNew = __builtin_amdgcn_rcpf(aPrev);            \
    float hs = fmaf(phe, (FE), g2);                       \
    float cz = fmaf(mom2C, z, hs);                        \
    float kl = fmaf(m2g2, rU, cz);                        \
    float W  = fmaf(CAu, u, z);                           \
    float zn = fmaf(CAGB, kl, W);                         \
    float un = fmaf(Fd, u, kl);                           \
    float e  = __builtin_amdgcn_exp2f(zn);                \
    aPrev = ePrev + 1.0f;                                 \
    ePrev = e; rU = rNew; z = zn; u = un; }

#define STEP2(F0, F1, SP, TP) {                           \
    float za = z, ua = u; STEP(F0);                       \
    float zb = z, ub_ = u; STEP(F1);                      \
    (SP)[(TP) * NM] = make_float4(za, ua, zb, ub_); }

#define STEP32(SP, BUF) \
    STEP2(BUF[0].x, BUF[0].y, SP, 0);  STEP2(BUF[0].z, BUF[0].w, SP, 1);  \
    STEP2(BUF[1].x, BUF[1].y, SP, 2);  STEP2(BUF[1].z, BUF[1].w, SP, 3);  \
    STEP2(BUF[2].x, BUF[2].y, SP, 4);  STEP2(BUF[2].z, BUF[2].w, SP, 5);  \
    STEP2(BUF[3].x, BUF[3].y, SP, 6);  STEP2(BUF[3].z, BUF[3].w, SP, 7);  \
    STEP2(BUF[4].x, BUF[4].y, SP, 8);  STEP2(BUF[4].z, BUF[4].w, SP, 9);  \
    STEP2(BUF[5].x, BUF[5].y, SP, 10); STEP2(BUF[5].z, BUF[5].w, SP, 11); \
    STEP2(BUF[6].x, BUF[6].y, SP, 12); STEP2(BUF[6].z, BUF[6].w, SP, 13); \
    STEP2(BUF[7].x, BUF[7].y, SP, 14); STEP2(BUF[7].z, BUF[7].w, SP, 15);

        for (int j = 0; j < NITER; j += 2) {
            float4* s0 = &lzu[j & 3][0][m];
            STEP32(s0, bufA);
            __syncthreads();
            // refill AFTER the barrier: loads fly during the next STEP32,
            // complete before the next drain; consumed at tile j+2.
            {
                const int jn = (j + 2 < NITER) ? (j + 2) : j;
#pragma unroll
                for (int i = 0; i < 8; ++i) bufA[i] = fe4[8 * jn + i];
            }

            float4* s1 = &lzu[(j + 1) & 3][0][m];
            STEP32(s1, bufB);
            __syncthreads();
            {
                const int jn = (j + 3 < NITER) ? (j + 3) : (j + 1);
#pragma unroll
                for (int i = 0; i < 8; ++i) bufB[i] = fe4[8 * jn + i];
            }
        }
        // pseudo-entry for u_{NT}: slot NITER&3 == 0, entry 0, .y = final u
        lzu[NITER & 3][0][m] = make_float4(0.0f, u, 0.0f, 0.0f);
        __syncthreads();   // barrier #NITER+1 (matched by storers)
#undef STEP32
#undef STEP2
#undef STEP
    } else {
        // ---------------- storer waves (w = 0,1) ----------------
        const int w = wid - 1;
        const float sg   = sigma[b * NM + m];
        const float dinv = 1.0f / (1.0f + k * sg);
        const float Gd   = k2 * dinv;

        float* yql = y_out + ((size_t)b * 2 * NM + m) * (size_t)NT;
        float* ypl = yql + (size_t)NM * NT;

        // HALF(tile, half): write dq/dp float4s [half*4 .. half*4+3] of `tile`.
        auto HALF = [&](int tile, int half) {
            const float4* sp  = &lzu[tile & 3][0][m];
            const float4* spn = &lzu[(tile + 1) & 3][0][m];
            float4* dq = reinterpret_cast<float4*>(yql + (size_t)SPI * tile) + half * 4;
            float4* dp = reinterpret_cast<float4*>(ypl + (size_t)SPI * tile) + half * 4;
#pragma unroll
            for (int i = half * 4; i < half * 4 + 4; ++i) {
                float4 va = sp[(2 * i) * NM];
                float4 vb = sp[(2 * i + 1) * NM];
                float  u2 = (i < 7) ? sp[(2 * i + 2) * NM].y : spn[0].y;
                dq[i - half * 4] = make_float4(invC * va.x, invC * va.z,
                                               invC * vb.x, invC * vb.z);
                dp[i - half * 4] = make_float4(Gd * (va.y + va.w), Gd * (va.w + vb.y),
                                               Gd * (vb.y + vb.w), Gd * (vb.w + u2));
            }
        };

        for (int j = 0; j < NITER; ++j) {
            __syncthreads();           // publishes tile j
            if ((j & 1) == w) {
                HALF(j, 0);            // phase A of my tile j
            } else if (j >= 1) {
                HALF(j - 1, 1);        // phase B of my tile j-1 (needs tile j's u)
            }
        }
        __syncthreads();               // publishes pseudo-entry (u_NT)
        if (((NITER - 1) & 1) == w) {
            HALF(NITER - 1, 1);        // phase B of the final tile
        }
    }
}

// w[b,t] = sum_m Phi_o[b,m] * y[b,m,t]  (fully parallel, memory/L3-bound)
__global__ void __launch_bounds__(256) w_kernel(
    const float* __restrict__ y,
    const float* __restrict__ Phi_o,
    float* __restrict__ w)
{
    const int b  = blockIdx.y;
    const int t4 = blockIdx.x * 256 + threadIdx.x;
    if (t4 >= NT / 4) return;

    const float4* yb = reinterpret_cast<const float4*>(y + (size_t)b * 2 * NM * NT);
    const float*  po = Phi_o + b * NM;

    float4 acc = make_float4(0.f, 0.f, 0.f, 0.f);
    #pragma unroll 8
    for (int mm = 0; mm < NM; ++mm) {
        float  c = po[mm];
        float4 v = yb[mm * (NT / 4) + t4];
        acc.x = fmaf(c, v.x, acc.x);
        acc.y = fmaf(c, v.y, acc.y);
        acc.z = fmaf(c, v.z, acc.z);
        acc.w = fmaf(c, v.w, acc.w);
    }
    reinterpret_cast<float4*>(w + (size_t)b * NT)[t4] = acc;
}

extern "C" void kernel_launch(void* const* d_in, const int* in_sizes, int n_in,
                              void* d_out, int out_size, void* d_ws, size_t ws_size,
                              hipStream_t stream)
{
    // inputs: 0=fs, 1=num_samples, 2=y0, 3=omega, 4=sigma, 5=gamma,
    //         6=Phi_e, 7=Phi_o, 8=fe_points
    const float* y0    = (const float*)d_in[2];
    const float* omega = (const float*)d_in[3];
    const float* sigma = (const float*)d_in[4];
    const float* gamma = (const float*)d_in[5];
    const float* Phi_e = (const float*)d_in[6];
    const float* Phi_o = (const float*)d_in[7];
    const float* fe    = (const float*)d_in[8];

    float* y_out = (float*)d_out;                    // (B, 2M, T)
    float* w_out = y_out + (size_t)NB * 2 * NM * NT; // (B, T)

    modal_scan_kernel<<<NB, 192, 0, stream>>>(y0, omega, sigma, gamma, Phi_e, fe, y_out);

    dim3 grid((NT / 4 + 255) / 256, NB);
    w_kernel<<<grid, 256, 0, stream>>>(y_out, Phi_o, w_out);
}

// Round 10
// 1989.952 us; speedup vs baseline: 1.1098x; 1.1098x over previous
//
#include <hip/hip_runtime.h>

// ModalVerlet: B=16, M=64, T=48000. 1 scan wave + 2 storer waves, decoupled by
// LDS sequence flags (NO per-tile __syncthreads).
//
// Why: __syncthreads lowers to "s_waitcnt vmcnt(0) lgkmcnt(0); s_barrier" on
// EVERY wave. R5-R8's flat ~71 cyc/step floor = scan math (~30) + coupling
// terms the barrier injects every tile: storers arrive late by their
// global_store ack drain (~300-500 cyc) and the scan drains its own fe loads.
// R9 proved load placement can't fix this (barrier = scheduling fence; the
// compiler was already hoisting R8's loads). So: remove the barrier.
//
// Protocol (4-slot LDS ring):
//   scan, per tile j: [every 2 tiles: spin until cons_seq covers tiles j-4,j-3]
//     STEP32 -> ds_writes into slot j&3; fe refill (compiler-hoistable);
//     s_waitcnt lgkmcnt(0); prod_seq = j+1.
//   storer w, tiles w, w+2, ...: spin until prod_seq >= tile+2 (tile AND
//     tile+1 published; tile+1 supplies the boundary u); read slot, compute
//     q=invC*z / p=Gd*(u+u'), issue 16 global_store_dwordx4;
//     s_waitcnt lgkmcnt(0); cons_seq[w] = tile+1.  (Slot reuse only needs the
//     LDS READS done - store acks stay in the storer's own 2-tile budget.)
// Final boundary u_NT via pseudo-entry in slot 0 + prod_seq = NITER+1.
//
// Scan math bit-identical to R7/R8 (absmax 2.0): 7 VALU + 2 trans per step,
// 3-fma loop chain, trans latency pipelined across steps, lag-2 r (coeff
// ~1e-8 path; error far below the scheme's fp32 drift).

#define NB 16
#define NM 64
#define NT 48000
#define SPI 32
#define NITER (NT / SPI) // 1500
#define NSLOT 4

__global__ void __launch_bounds__(192, 1) modal_scan_kernel(
    const float* __restrict__ y0,
    const float* __restrict__ omega,
    const float* __restrict__ sigma,
    const float* __restrict__ gamma,
    const float* __restrict__ Phi_e,
    const float* __restrict__ fe_points,
    float* __restrict__ y_out)
{
    const int b   = blockIdx.x;
    const int wid = threadIdx.x >> 6;
    const int m   = threadIdx.x & 63;

    __shared__ float4 lzu[NSLOT][SPI / 2][NM]; // (z_t,u_t,z_{t+1},u_{t+1}); 64KB
    __shared__ volatile int prod_seq;
    __shared__ volatile int cons_seq[2];

    if (threadIdx.x == 0) { prod_seq = 0; cons_seq[0] = 0; cons_seq[1] = 0; }
    __syncthreads(); // the ONLY block barrier (flag init)

    const float k    = 1.0f / 48000.0f;
    const float k2   = 0.5f * k;
    const float invC = 0.34657359027997264f; // ln(2)/2

    if (wid == 0) {
        // ---------------- scan wave ----------------
        const float om  = omega[b * NM + m];
        const float sg  = sigma[b * NM + m];
        const float g   = gamma[b];
        const float phe = Phi_e[b * NM + m];
        const float om2 = om * om;
        const float g2  = g * g;

        const float E    = 1.0f - k * sg;
        const float dinv = 1.0f / (1.0f + k * sg);
        const float A    = k * E;
        const float Bc   = k * k2;
        const float Fd   = E * dinv;
        const float Gd   = k2 * dinv;
        const float AGB  = A * Gd + Bc;
        const float m2g2 = -2.0f * g2;

        const float C    = 2.885390081777927f;   // 2*log2(e)
        const float CA   = C * A;
        const float CAGB = C * AGB;
        const float mom2C = -om2 * invC;
        const float GdF1 = Gd * (1.0f + Fd);
        const float CAu  = CA * GdF1;

        const float q0v = y0[b * 2 * NM + m];
        const float p0v = y0[b * 2 * NM + NM + m];

        const float4* fe4 = reinterpret_cast<const float4*>(fe_points + (size_t)b * NT);

        float4 bufA[8], bufB[8];
#pragma unroll
        for (int i = 0; i < 8; ++i) bufA[i] = fe4[i];
#pragma unroll
        for (int i = 0; i < 8; ++i) bufB[i] = fe4[8 + i];

        // ---- preamble: state 0 + trans pipeline priming ----
        float z  = C * q0v;
        float e0 = __builtin_amdgcn_exp2f(z);
        float a0 = e0 + 1.0f;
        float r0 = __builtin_amdgcn_rcpf(a0);
        float u;
        {
            float hs0 = fmaf(phe, bufA[0].x, g2);
            float cz0 = fmaf(mom2C, z, hs0);
            float c0  = fmaf(m2g2, r0, cz0);
            u = fmaf(-Gd, c0, p0v) / GdF1;   // u_0 : p_0 = Gd*(u_0+u_1)
        }
        float rU = r0, aPrev = a0, ePrev = e0;

#define STEP(FE) {                                        \
    float rNew = __builtin_amdgcn_rcpf(aPrev);            \
    float hs = fmaf(phe, (FE), g2);                       \
    float cz = fmaf(mom2C, z, hs);                        \
    float kl = fmaf(m2g2, rU, cz);                        \
    float W  = fmaf(CAu, u, z);                           \
    float zn = fmaf(CAGB, kl, W);                         \
    float un = fmaf(Fd, u, kl);                           \
    float e  = __builtin_amdgcn_exp2f(zn);                \
    aPrev = ePrev + 1.0f;                                 \
    ePrev = e; rU = rNew; z = zn; u = un; }

#define STEP2(F0, F1, SP, TP) {                           \
    float za = z, ua = u; STEP(F0);                       \
    float zb = z, ub_ = u; STEP(F1);                      \
    (SP)[(TP) * NM] = make_float4(za, ua, zb, ub_); }

#define STEP32(SP, BUF) \
    STEP2(BUF[0].x, BUF[0].y, SP, 0);  STEP2(BUF[0].z, BUF[0].w, SP, 1);  \
    STEP2(BUF[1].x, BUF[1].y, SP, 2);  STEP2(BUF[1].z, BUF[1].w, SP, 3);  \
    STEP2(BUF[2].x, BUF[2].y, SP, 4);  STEP2(BUF[2].z, BUF[2].w, SP, 5);  \
    STEP2(BUF[3].x, BUF[3].y, SP, 6);  STEP2(BUF[3].z, BUF[3].w, SP, 7);  \
    STEP2(BUF[4].x, BUF[4].y, SP, 8);  STEP2(BUF[4].z, BUF[4].w, SP, 9);  \
    STEP2(BUF[5].x, BUF[5].y, SP, 10); STEP2(BUF[5].z, BUF[5].w, SP, 11); \
    STEP2(BUF[6].x, BUF[6].y, SP, 12); STEP2(BUF[6].z, BUF[6].w, SP, 13); \
    STEP2(BUF[7].x, BUF[7].y, SP, 14); STEP2(BUF[7].z, BUF[7].w, SP, 15);

        for (int j = 0; j < NITER; j += 2) {
            // ring backpressure for slots (j&3) and ((j+1)&3): tiles j-4 and
            // j-3 must be read-done. Parities: (j-4)&1==0 -> cons_seq[0],
            // (j-3)&1==1 -> cons_seq[1]. Usually satisfied immediately.
            if (j >= 4) {
                while (cons_seq[0] < j - 3 || cons_seq[1] < j - 2)
                    __builtin_amdgcn_s_sleep(0);
                __asm__ volatile("" ::: "memory");
            }

            float4* s0 = &lzu[j & 3][0][m];
            STEP32(s0, bufA);
            {
                const int jn = (j + 2 < NITER) ? (j + 2) : j;
#pragma unroll
                for (int i = 0; i < 8; ++i) bufA[i] = fe4[8 * jn + i];
            }
            __asm__ volatile("s_waitcnt lgkmcnt(0)" ::: "memory");
            prod_seq = j + 1;

            float4* s1 = &lzu[(j + 1) & 3][0][m];
            STEP32(s1, bufB);
            {
                const int jn = (j + 3 < NITER) ? (j + 3) : (j + 1);
#pragma unroll
                for (int i = 0; i < 8; ++i) bufB[i] = fe4[8 * jn + i];
            }
            __asm__ volatile("s_waitcnt lgkmcnt(0)" ::: "memory");
            prod_seq = j + 2;
        }

        // pseudo-entry for u_{NT}: lives in slot (NITER&3)==0, entry 0 (.y).
        // Slot 0 currently holds tile NITER-4 (=1496, parity 0): wait for it.
        while (cons_seq[0] < NITER - 3) __builtin_amdgcn_s_sleep(0);
        __asm__ volatile("" ::: "memory");
        lzu[0][0][m] = make_float4(0.0f, u, 0.0f, 0.0f);
        __asm__ volatile("s_waitcnt lgkmcnt(0)" ::: "memory");
        prod_seq = NITER + 1;
#undef STEP32
#undef STEP2
#undef STEP
    } else {
        // ---------------- storer waves (w = 0,1; tiles of parity w) --------
        const int w = wid - 1;
        const float sg   = sigma[b * NM + m];
        const float dinv = 1.0f / (1.0f + k * sg);
        const float Gd   = k2 * dinv;

        float* yql = y_out + ((size_t)b * 2 * NM + m) * (size_t)NT;
        float* ypl = yql + (size_t)NM * NT;

        for (int tile = w; tile < NITER; tile += 2) {
            // need tile AND tile+1 published (tile+1 -> boundary u). For the
            // last tile, tile+2 == NITER+1 == the pseudo-entry flag.
            const int need = tile + 2;
            while (prod_seq < need) __builtin_amdgcn_s_sleep(1);
            __asm__ volatile("" ::: "memory");

            const float4* sp  = &lzu[tile & 3][0][m];
            const float4* spn = &lzu[(tile + 1) & 3][0][m];
            float4* dq = reinterpret_cast<float4*>(yql + (size_t)SPI * tile);
            float4* dp = reinterpret_cast<float4*>(ypl + (size_t)SPI * tile);
#pragma unroll
            for (int i = 0; i < 8; ++i) {
                float4 va = sp[(2 * i) * NM];
                float4 vb = sp[(2 * i + 1) * NM];
                float  u2 = (i < 7) ? sp[(2 * i + 2) * NM].y : spn[0].y;
                dq[i] = make_float4(invC * va.x, invC * va.z,
                                    invC * vb.x, invC * vb.z);
                dp[i] = make_float4(Gd * (va.y + va.w), Gd * (va.w + vb.y),
                                    Gd * (vb.y + vb.w), Gd * (vb.w + u2));
            }
            // LDS reads done (results consumed into store data above); slot
            // may be reused. Store ACKs intentionally NOT waited on here.
            __asm__ volatile("s_waitcnt lgkmcnt(0)" ::: "memory");
            cons_seq[w] = tile + 1;
        }
    }
}

// w[b,t] = sum_m Phi_o[b,m] * y[b,m,t]  (fully parallel, memory/L3-bound)
__global__ void __launch_bounds__(256) w_kernel(
    const float* __restrict__ y,
    const float* __restrict__ Phi_o,
    float* __restrict__ w)
{
    const int b  = blockIdx.y;
    const int t4 = blockIdx.x * 256 + threadIdx.x;
    if (t4 >= NT / 4) return;

    const float4* yb = reinterpret_cast<const float4*>(y + (size_t)b * 2 * NM * NT);
    const float*  po = Phi_o + b * NM;

    float4 acc = make_float4(0.f, 0.f, 0.f, 0.f);
    #pragma unroll 8
    for (int mm = 0; mm < NM; ++mm) {
        float  c = po[mm];
        float4 v = yb[mm * (NT / 4) + t4];
        acc.x = fmaf(c, v.x, acc.x);
        acc.y = fmaf(c, v.y, acc.y);
        acc.z = fmaf(c, v.z, acc.z);
        acc.w = fmaf(c, v.w, acc.w);
    }
    reinterpret_cast<float4*>(w + (size_t)b * NT)[t4] = acc;
}

extern "C" void kernel_launch(void* const* d_in, const int* in_sizes, int n_in,
                              void* d_out, int out_size, void* d_ws, size_t ws_size,
                              hipStream_t stream)
{
    // inputs: 0=fs, 1=num_samples, 2=y0, 3=omega, 4=sigma, 5=gamma,
    //         6=Phi_e, 7=Phi_o, 8=fe_points
    const float* y0    = (const float*)d_in[2];
    const float* omega = (const float*)d_in[3];
    const float* sigma = (const float*)d_in[4];
    const float* gamma = (const float*)d_in[5];
    const float* Phi_e = (const float*)d_in[6];
    const float* Phi_o = (const float*)d_in[7];
    const float* fe    = (const float*)d_in[8];

    float* y_out = (float*)d_out;                    // (B, 2M, T)
    float* w_out = y_out + (size_t)NB * 2 * NM * NT; // (B, T)

    modal_scan_kernel<<<NB, 192, 0, stream>>>(y0, omega, sigma, gamma, Phi_e, fe, y_out);

    dim3 grid((NT / 4 + 255) / 256, NB);
    w_kernel<<<grid, 256, 0, stream>>>(y_out, Phi_o, w_out);
}

// Round 11
// 1718.840 us; speedup vs baseline: 1.2849x; 1.1577x over previous
//
#include <hip/hip_runtime.h>

// ModalVerlet: B=16, M=64, T=48000. 3-wave specialization (R8 skeleton, best
// measured): 1 scan wave + 2 storer waves, per-tile __syncthreads, 4-slot ring.
//
// R11 change: transcendental-free steady-state step. R5-R8 sat at a flat
// ~70 cyc/step regardless of chain length / storer org / barrier org; the
// only invariant cost left is the 2 trans/step (v_exp_f32+v_rcp_f32 issue at
// quarter rate ~16cyc wave64 -> ~32 cyc/step). Replace the per-step tanh with
// the addition identity on the carried value w ~ tanh(q):
//     tanh(a+d) = (w + d)/(1 + w*d),  1/(1+x) ~ 1 - x + x^2   (x = w*d ~ 4e-4)
// using lag-1 w in the force c = cb + g2*w (telescoping-safe, ~1e-6 output
// perturbation), and re-anchoring w EXACTLY once per 32-step tile via
// w = 1 - 2*rcp(exp2(z)+1), Dp = 0 (drift window <= 32 steps -> |w err| <=
// ~6e-7; anchor sits before the barrier, off the critical path).
// Step = 13 VALU, 0 trans: z-chain cz->c->zn (3 fma) + w-chain (4 ops with a
// full step of slack). p moved to storer: p_s = Gd*(u_s+u_{s+1}) (exact).
//
// Storers: as R8 — alternate tiles, each tile split across two barrier
// intervals (phase A: dq/dp[0..3] at interval j, phase B: [4..7] at j+1);
// boundary u from next tile's entry 0; final u via pseudo-entry + 1 barrier.

#define NB 16
#define NM 64
#define NT 48000
#define SPI 32
#define NITER (NT / SPI) // 1500
#define NSLOT 4

__global__ void __launch_bounds__(192, 1) modal_scan_kernel(
    const float* __restrict__ y0,
    const float* __restrict__ omega,
    const float* __restrict__ sigma,
    const float* __restrict__ gamma,
    const float* __restrict__ Phi_e,
    const float* __restrict__ fe_points,
    float* __restrict__ y_out)
{
    const int b   = blockIdx.x;
    const int wid = threadIdx.x >> 6;
    const int m   = threadIdx.x & 63;

    __shared__ float4 lzu[NSLOT][SPI / 2][NM]; // (z_t,u_t,z_{t+1},u_{t+1}); 64KB

    const float k    = 1.0f / 48000.0f;
    const float k2   = 0.5f * k;
    const float invC = 0.34657359027997264f; // ln(2)/2

    if (wid == 0) {
        // ---------------- scan wave ----------------
        const float om  = omega[b * NM + m];
        const float sg  = sigma[b * NM + m];
        const float g   = gamma[b];
        const float phe = Phi_e[b * NM + m];
        const float om2 = om * om;
        const float g2  = g * g;

        const float E    = 1.0f - k * sg;
        const float dinv = 1.0f / (1.0f + k * sg);
        const float A    = k * E;
        const float Bc   = k * k2;
        const float Fd   = E * dinv;
        const float Gd   = k2 * dinv;
        const float AGB  = A * Gd + Bc;

        const float C    = 2.885390081777927f;   // 2*log2(e)
        const float CA   = C * A;
        const float CAGB = C * AGB;
        const float mom2C = -om2 * invC;
        const float GdF1 = Gd * (1.0f + Fd);
        const float CAu  = CA * GdF1;

        const float q0v = y0[b * 2 * NM + m];
        const float p0v = y0[b * 2 * NM + NM + m];

        const float4* fe4 = reinterpret_cast<const float4*>(fe_points + (size_t)b * NT);

        float4 bufA[8], bufB[8];
#pragma unroll
        for (int i = 0; i < 8; ++i) bufA[i] = fe4[i];
#pragma unroll
        for (int i = 0; i < 8; ++i) bufB[i] = fe4[8 + i];

        // ---- preamble: state 0 ----
        float z  = C * q0v;
        float w, u;
        {
            float e0 = __builtin_amdgcn_exp2f(z);
            float r0 = __builtin_amdgcn_rcpf(e0 + 1.0f);
            w = fmaf(-2.0f, r0, 1.0f);               // tanh(q_0), lag-0 at step 0
            float hs0 = phe * bufA[0].x;
            float cz0 = fmaf(mom2C, z, hs0);
            float c0  = fmaf(g2, w, cz0);
            u = fmaf(-Gd, c0, p0v) / GdF1;           // u_0 : p_0 = Gd*(u_0+u_1)
        }
        float Dp = 0.0f;  // q-units increment spanning previous step (none yet)

        // STEP at state s: c_s uses w ~ tanh(q_{s-1}) (lag-1); w advances to
        // tanh(q_s) via the addition identity with Dp = q_s - q_{s-1}.
#define STEP(FE) {                                        \
    float hs = phe * (FE);                                \
    float cz = fmaf(mom2C, z, hs);                        \
    float c  = fmaf(g2, w, cz);                           \
    float W  = fmaf(CAu, u, z);                           \
    float zn = fmaf(CAGB, c, W);        /* z_{s+1} */     \
    float un = fmaf(Fd, u, c);          /* u_{s+1} */     \
    float x  = w * Dp;                                    \
    float xm = x - 1.0f;                                  \
    float iv = fmaf(x, xm, 1.0f);       /* ~1/(1+x) */    \
    float nm = w + Dp;                                    \
    float wn = nm * iv;                 /* tanh(q_s) */   \
    float dz = zn - z;                                    \
    Dp = invC * dz;                                       \
    w = wn; z = zn; u = un; }

#define STEP2(F0, F1, SP, TP) {                           \
    float za = z, ua = u; STEP(F0);                       \
    float zb = z, ub_ = u; STEP(F1);                      \
    (SP)[(TP) * NM] = make_float4(za, ua, zb, ub_); }

#define STEP32(SP, BUF) \
    STEP2(BUF[0].x, BUF[0].y, SP, 0);  STEP2(BUF[0].z, BUF[0].w, SP, 1);  \
    STEP2(BUF[1].x, BUF[1].y, SP, 2);  STEP2(BUF[1].z, BUF[1].w, SP, 3);  \
    STEP2(BUF[2].x, BUF[2].y, SP, 4);  STEP2(BUF[2].z, BUF[2].w, SP, 5);  \
    STEP2(BUF[3].x, BUF[3].y, SP, 6);  STEP2(BUF[3].z, BUF[3].w, SP, 7);  \
    STEP2(BUF[4].x, BUF[4].y, SP, 8);  STEP2(BUF[4].z, BUF[4].w, SP, 9);  \
    STEP2(BUF[5].x, BUF[5].y, SP, 10); STEP2(BUF[5].z, BUF[5].w, SP, 11); \
    STEP2(BUF[6].x, BUF[6].y, SP, 12); STEP2(BUF[6].z, BUF[6].w, SP, 13); \
    STEP2(BUF[7].x, BUF[7].y, SP, 14); STEP2(BUF[7].z, BUF[7].w, SP, 15);

        // Exact re-anchor of w (2 trans per 32 steps, off the critical path):
        // w := tanh(q at current z) — lag-0 for the next step (telescoping-
        // safe), then Dp = 0 so the next increment is a no-op onto the anchor.
#define ANCHOR() {                                        \
    float ea = __builtin_amdgcn_exp2f(z);                 \
    float ra = __builtin_amdgcn_rcpf(ea + 1.0f);          \
    w = fmaf(-2.0f, ra, 1.0f);                            \
    Dp = 0.0f; }

        for (int j = 0; j < NITER; j += 2) {
            float4* s0 = &lzu[j & 3][0][m];
            STEP32(s0, bufA);
            {
                const int jn = (j + 2 < NITER) ? (j + 2) : j;
#pragma unroll
                for (int i = 0; i < 8; ++i) bufA[i] = fe4[8 * jn + i];
            }
            ANCHOR();
            __syncthreads();

            float4* s1 = &lzu[(j + 1) & 3][0][m];
            STEP32(s1, bufB);
            {
                const int jn = (j + 3 < NITER) ? (j + 3) : (j + 1);
#pragma unroll
                for (int i = 0; i < 8; ++i) bufB[i] = fe4[8 * jn + i];
            }
            ANCHOR();
            __syncthreads();
        }
        // pseudo-entry for u_{NT}: slot (NITER&3)==0, entry 0, .y = final u
        lzu[0][0][m] = make_float4(0.0f, u, 0.0f, 0.0f);
        __syncthreads();   // barrier #NITER+1 (matched by storers)
#undef ANCHOR
#undef STEP32
#undef STEP2
#undef STEP
    } else {
        // ---------------- storer waves (w = 0,1) ----------------
        const int w = wid - 1;
        const float sg   = sigma[b * NM + m];
        const float dinv = 1.0f / (1.0f + k * sg);
        const float Gd   = k2 * dinv;

        float* yql = y_out + ((size_t)b * 2 * NM + m) * (size_t)NT;
        float* ypl = yql + (size_t)NM * NT;

        // HALF(tile, half): write dq/dp float4s [half*4 .. half*4+3] of `tile`.
        auto HALF = [&](int tile, int half) {
            const float4* sp  = &lzu[tile & 3][0][m];
            const float4* spn = &lzu[(tile + 1) & 3][0][m];
            float4* dq = reinterpret_cast<float4*>(yql + (size_t)SPI * tile) + half * 4;
            float4* dp = reinterpret_cast<float4*>(ypl + (size_t)SPI * tile) + half * 4;
#pragma unroll
            for (int i = half * 4; i < half * 4 + 4; ++i) {
                float4 va = sp[(2 * i) * NM];
                float4 vb = sp[(2 * i + 1) * NM];
                float  u2 = (i < 7) ? sp[(2 * i + 2) * NM].y : spn[0].y;
                dq[i - half * 4] = make_float4(invC * va.x, invC * va.z,
                                               invC * vb.x, invC * vb.z);
                dp[i - half * 4] = make_float4(Gd * (va.y + va.w), Gd * (va.w + vb.y),
                                               Gd * (vb.y + vb.w), Gd * (vb.w + u2));
            }
        };

        for (int j = 0; j < NITER; ++j) {
            __syncthreads();           // publishes tile j
            if ((j & 1) == w) {
                HALF(j, 0);            // phase A of my tile j
            } else if (j >= 1) {
                HALF(j - 1, 1);        // phase B of my tile j-1 (needs tile j's u)
            }
        }
        __syncthreads();               // publishes pseudo-entry (u_NT)
        if (((NITER - 1) & 1) == w) {
            HALF(NITER - 1, 1);        // phase B of the final tile
        }
    }
}

// w[b,t] = sum_m Phi_o[b,m] * y[b,m,t]  (fully parallel, memory/L3-bound)
__global__ void __launch_bounds__(256) w_kernel(
    const float* __restrict__ y,
    const float* __restrict__ Phi_o,
    float* __restrict__ w)
{
    const int b  = blockIdx.y;
    const int t4 = blockIdx.x * 256 + threadIdx.x;
    if (t4 >= NT / 4) return;

    const float4* yb = reinterpret_cast<const float4*>(y + (size_t)b * 2 * NM * NT);
    const float*  po = Phi_o + b * NM;

    float4 acc = make_float4(0.f, 0.f, 0.f, 0.f);
    #pragma unroll 8
    for (int mm = 0; mm < NM; ++mm) {
        float  c = po[mm];
        float4 v = yb[mm * (NT / 4) + t4];
        acc.x = fmaf(c, v.x, acc.x);
        acc.y = fmaf(c, v.y, acc.y);
        acc.z = fmaf(c, v.z, acc.z);
        acc.w = fmaf(c, v.w, acc.w);
    }
    reinterpret_cast<float4*>(w + (size_t)b * NT)[t4] = acc;
}

extern "C" void kernel_launch(void* const* d_in, const int* in_sizes, int n_in,
                              void* d_out, int out_size, void* d_ws, size_t ws_size,
                              hipStream_t stream)
{
    // inputs: 0=fs, 1=num_samples, 2=y0, 3=omega, 4=sigma, 5=gamma,
    //         6=Phi_e, 7=Phi_o, 8=fe_points
    const float* y0    = (const float*)d_in[2];
    const float* omega = (const float*)d_in[3];
    const float* sigma = (const float*)d_in[4];
    const float* gamma = (const float*)d_in[5];
    const float* Phi_e = (const float*)d_in[6];
    const float* Phi_o = (const float*)d_in[7];
    const float* fe    = (const float*)d_in[8];

    float* y_out = (float*)d_out;                    // (B, 2M, T)
    float* w_out = y_out + (size_t)NB * 2 * NM * NT; // (B, T)

    modal_scan_kernel<<<NB, 192, 0, stream>>>(y0, omega, sigma, gamma, Phi_e, fe, y_out);

    dim3 grid((NT / 4 + 255) / 256, NB);
    w_kernel<<<grid, 256, 0, stream>>>(y_out, Phi_o, w_out);
}